// Round 8
// baseline (275.205 us; speedup 1.0000x reference)
//
#include <hip/hip_runtime.h>

#define HIDDEN 2048
#define NHEADS 32
#define NKV 8
#define HD 64
#define BATCH 2
#define SEQ 2048
#define MROWS (BATCH*SEQ)        // 4096
#define KVDIM (NKV*HD)           // 512
#define QKVN (HIDDEN + 2*KVDIM)  // 3072

typedef __bf16 bf16x8 __attribute__((ext_vector_type(8)));
typedef __bf16 bf16x4 __attribute__((ext_vector_type(4)));
typedef float f32x4 __attribute__((ext_vector_type(4)));

__device__ inline f32x4 mfma32(bf16x8 a, bf16x8 b, f32x4 c) {
    return __builtin_amdgcn_mfma_f32_16x16x32_bf16(a, b, c, 0, 0, 0);
}

// async global->LDS, 16B per lane; lds base must be wave-uniform (HW: base + lane*16)
__device__ inline void gld16(const __bf16* g, __bf16* l) {
    __builtin_amdgcn_global_load_lds((const __attribute__((address_space(1))) void*)g,
                                     (__attribute__((address_space(3))) void*)l, 16, 0, 0);
}

// ---------------- fused cast fp32 -> bf16 for all 5 tensors ----------------
__global__ __launch_bounds__(256) void cast_all(const float* __restrict__ x,
                                                const float* __restrict__ wq,
                                                const float* __restrict__ wk,
                                                const float* __restrict__ wv,
                                                const float* __restrict__ wo,
                                                __bf16* __restrict__ xb,
                                                __bf16* __restrict__ wqkv,
                                                __bf16* __restrict__ wob,
                                                float qscale) {
    int blk = blockIdx.x;
    const float* src; __bf16* dst; float sc = 1.0f; size_t off;
    if (blk < 8192)        { src = x;  dst = xb;   off = (size_t)blk * 1024; }
    else if (blk < 12288)  { src = wq; dst = wqkv; off = (size_t)(blk - 8192) * 1024; sc = qscale; }
    else if (blk < 13312)  { src = wk; dst = wqkv + (size_t)HIDDEN * HIDDEN; off = (size_t)(blk - 12288) * 1024; }
    else if (blk < 14336)  { src = wv; dst = wqkv + (size_t)(HIDDEN + KVDIM) * HIDDEN; off = (size_t)(blk - 13312) * 1024; }
    else                   { src = wo; dst = wob;  off = (size_t)(blk - 14336) * 1024; }
    size_t i4 = off + (size_t)threadIdx.x * 4;
    float4 f = *(const float4*)(src + i4);
    dst[i4 + 0] = (__bf16)(f.x * sc);
    dst[i4 + 1] = (__bf16)(f.y * sc);
    dst[i4 + 2] = (__bf16)(f.z * sc);
    dst[i4 + 3] = (__bf16)(f.w * sc);
}

__device__ inline void store_val(__bf16* C, size_t idx, float v) { C[idx] = (__bf16)v; }
__device__ inline void store_val(float* C, size_t idx, float v) { C[idx] = v; }

// ---------------- GEMM (gemm2): C = A(M,K) @ B(N,K)^T; 128^2, BK=32 ----------
template <typename OutT>
__global__ __launch_bounds__(256) void gemm128(const __bf16* __restrict__ A,
                                               const __bf16* __restrict__ B,
                                               OutT* __restrict__ C,
                                               int M, int N, int K) {
    __shared__ __bf16 As[2][128][32];
    __shared__ __bf16 Bs[2][128][32];
    const int tid  = threadIdx.x;
    const int lane = tid & 63;
    const int w    = tid >> 6;
    const int col  = lane & 15;
    const int quad = lane >> 4;
    const int m0 = blockIdx.y * 128;
    const int n0 = blockIdx.x * 128;
    const int wm = (w >> 1) * 64;
    const int wn = (w & 1) * 64;

    f32x4 acc[4][4];
    #pragma unroll
    for (int i = 0; i < 4; i++)
        #pragma unroll
        for (int j = 0; j < 4; j++) acc[i][j] = (f32x4){0.f,0.f,0.f,0.f};

    const int lrow = lane >> 2;        // 0..15
    const int lcol = (lane & 3) * 8;   // 0,8,16,24

    auto stage = [&](int k0, int buf) {
        #pragma unroll
        for (int c = 0; c < 4; c++) {
            int chunk = w * 4 + c;
            if (chunk < 8) {
                const __bf16* g = A + (size_t)(m0 + chunk*16 + lrow) * K + k0 + lcol;
                gld16(g, &As[buf][chunk*16][0]);
            } else {
                int bc = chunk - 8;
                const __bf16* g = B + (size_t)(n0 + bc*16 + lrow) * K + k0 + lcol;
                gld16(g, &Bs[buf][bc*16][0]);
            }
        }
    };

    const int nk = K / 32;
    stage(0, 0);
    for (int ki = 0; ki < nk; ki++) {
        const int buf = ki & 1;
        __syncthreads();                      // drains stage(ki) DMA; frees buf^1
        if (ki + 1 < nk) stage((ki + 1) * 32, buf ^ 1);   // overlaps compute below

        bf16x8 af[4], bfr[4];
        #pragma unroll
        for (int i = 0; i < 4; i++) af[i]  = *(const bf16x8*)&As[buf][wm + i*16 + col][quad*8];
        #pragma unroll
        for (int j = 0; j < 4; j++) bfr[j] = *(const bf16x8*)&Bs[buf][wn + j*16 + col][quad*8];
        #pragma unroll
        for (int i = 0; i < 4; i++)
            #pragma unroll
            for (int j = 0; j < 4; j++)
                acc[i][j] = __builtin_amdgcn_mfma_f32_16x16x32_bf16(af[i], bfr[j], acc[i][j], 0, 0, 0);
    }

    #pragma unroll
    for (int i = 0; i < 4; i++) {
        #pragma unroll
        for (int r = 0; r < 4; r++) {
            int mrow = m0 + wm + i*16 + quad*4 + r;
            size_t base = (size_t)mrow * N + n0 + wn;
            #pragma unroll
            for (int j = 0; j < 4; j++)
                store_val(C, base + j*16 + col, acc[i][j][r]);
        }
    }
}

// ---------------- GEMM (gemm1): 256x192 tile, BK=64, free-run pipeline --------
// ONE s_barrier + ONE vmcnt(0)+lgkmcnt(0) per K-tile; operand subtiles ds_read
// one phase ahead so counted lgkm waits drain under the previous MFMA cluster.
// Whole-tile DMA batch issued at t for t+2 (T4). Both-sides XOR swizzle
// (r6: conflicts 6.3M -> 0). BN=192: grid 16x16 = 256 = 1 block/CU.
__global__ __launch_bounds__(512, 2) void gemm256(const __bf16* __restrict__ A,
                                                  const __bf16* __restrict__ B,
                                                  __bf16* __restrict__ C,
                                                  int M, int N, int K) {
    __shared__ __bf16 As[2][256][64];   // 64 KB
    __shared__ __bf16 Bs[2][192][64];   // 48 KB
    const int tid  = threadIdx.x;
    const int lane = tid & 63;
    const int w    = tid >> 6;       // 0..7
    const int wr   = w >> 2;         // 0..1 (M)
    const int wc   = w & 3;          // 0..3 (N)
    const int col  = lane & 15;
    const int quad = lane >> 4;
    const int m0 = blockIdx.y * 256;
    const int n0 = blockIdx.x * 192;
    const int nk = K >> 6;

    f32x4 acc[8][3];
    #pragma unroll
    for (int i = 0; i < 8; i++)
        #pragma unroll
        for (int j = 0; j < 3; j++) acc[i][j] = (f32x4){0.f,0.f,0.f,0.f};

    bf16x8 amh0[4][2];   // A rows wr*128 + 0..63    (used p0,p1)
    bf16x8 amh1[4][2];   // A rows wr*128 + 64..127  (used p2,p3)
    bf16x8 b01[2][2];    // B rows wc*48 + 0..31     (used p0,p2)
    bf16x8 b2v[2];       // B rows wc*48 + 32..47    (used p1,p3)

    const int r8 = lane >> 3, c8 = lane & 7;
    const __bf16* pA0 = A + (size_t)(m0 + w*16 +     r8) * K + ((c8 ^ quad) * 8);
    const __bf16* pA1 = A + (size_t)(m0 + w*16 + 8 + r8) * K + ((c8 ^ (4 + quad)) * 8);
    const __bf16* pB  = B + (size_t)(n0 + w*8 +      r8) * K + ((c8 ^ ((w & 1) * 4 + quad)) * 8);
    const int rsw = col >> 1;    // read-side swizzle term

    auto issue = [&](int tt) {   // whole-tile staging batch: 7 gld16/wave
        if (tt < nk) {
            int b = tt & 1; size_t ko = (size_t)tt * 64;
            gld16(pA0 + ko,                  &As[b][w*16][0]);
            gld16(pA1 + ko,                  &As[b][w*16 + 8][0]);
            gld16(pA0 + (size_t)128*K + ko,  &As[b][128 + w*16][0]);
            gld16(pA1 + (size_t)128*K + ko,  &As[b][128 + w*16 + 8][0]);
            gld16(pB + ko,                   &Bs[b][w*8][0]);
            gld16(pB + (size_t)64*K + ko,    &Bs[b][64 + w*8][0]);
            gld16(pB + (size_t)128*K + ko,   &Bs[b][128 + w*8][0]);
        }
    };
    auto rdA = [&](bf16x8 (&dst)[4][2], int b, int rowbase) {
        #pragma unroll
        for (int i = 0; i < 4; i++) {
            const __bf16* rp = &As[b][rowbase + i*16 + col][0];
            #pragma unroll
            for (int kk = 0; kk < 2; kk++)
                dst[i][kk] = *(const bf16x8*)(rp + (((kk*4 + quad) ^ rsw) * 8));
        }
    };
    auto rdB01 = [&](int b) {
        #pragma unroll
        for (int j = 0; j < 2; j++) {
            const __bf16* rp = &Bs[b][wc*48 + j*16 + col][0];
            #pragma unroll
            for (int kk = 0; kk < 2; kk++)
                b01[j][kk] = *(const bf16x8*)(rp + (((kk*4 + quad) ^ rsw) * 8));
        }
    };

    issue(0); issue(1);
    __asm__ volatile("s_waitcnt vmcnt(7)" ::: "memory");   // tile0 landed (tile1 in flight)
    __builtin_amdgcn_s_barrier();
    __asm__ volatile("" ::: "memory");
    rdA(amh0, 0, wr*128);
    rdB01(0);

    for (int t = 0; t < nk; ++t) {
        const int buf = t & 1;
        {
            const __bf16* rp = &Bs[buf][wc*48 + 32 + col][0];
            #pragma unroll
            for (int kk = 0; kk < 2; kk++)
                b2v[kk] = *(const bf16x8*)(rp + (((kk*4 + quad) ^ rsw) * 8));
        }
        __builtin_amdgcn_s_setprio(1);
        #pragma unroll
        for (int i = 0; i < 4; i++)
            #pragma unroll
            for (int j = 0; j < 2; j++)
                #pragma unroll
                for (int kk = 0; kk < 2; kk++)
                    acc[i][j] = mfma32(amh0[i][kk], b01[j][kk], acc[i][j]);
        __builtin_amdgcn_s_setprio(0);
        rdA(amh1, buf, wr*128 + 64);
        __builtin_amdgcn_s_setprio(1);
        #pragma unroll
        for (int i = 0; i < 4; i++)
            #pragma unroll
            for (int kk = 0; kk < 2; kk++)
                acc[i][2] = mfma32(amh0[i][kk], b2v[kk], acc[i][2]);
        __builtin_amdgcn_s_setprio(0);
        __builtin_amdgcn_s_setprio(1);
        #pragma unroll
        for (int i = 0; i < 4; i++)
            #pragma unroll
            for (int j = 0; j < 2; j++)
                #pragma unroll
                for (int kk = 0; kk < 2; kk++)
                    acc[4+i][j] = mfma32(amh1[i][kk], b01[j][kk], acc[4+i][j]);
        __builtin_amdgcn_s_setprio(0);

        __asm__ volatile("s_waitcnt vmcnt(0) lgkmcnt(0)" ::: "memory");
        __builtin_amdgcn_sched_barrier(0);
        __builtin_amdgcn_s_barrier();
        __asm__ volatile("" ::: "memory");

        if (t + 1 < nk) {
            rdA(amh0, buf ^ 1, wr*128);
            rdB01(buf ^ 1);
        }
        issue(t + 2);

        __builtin_amdgcn_s_setprio(1);
        #pragma unroll
        for (int i = 0; i < 4; i++)
            #pragma unroll
            for (int kk = 0; kk < 2; kk++)
                acc[4+i][2] = mfma32(amh1[i][kk], b2v[kk], acc[4+i][2]);
        __builtin_amdgcn_s_setprio(0);
    }

    #pragma unroll
    for (int i16 = 0; i16 < 8; i16++) {
        #pragma unroll
        for (int r = 0; r < 4; r++) {
            size_t base = (size_t)(m0 + wr*128 + i16*16 + quad*4 + r) * N + n0 + wc*48;
            #pragma unroll
            for (int j = 0; j < 3; j++)
                C[base + j*16 + col] = (__bf16)acc[i16][j][r];
        }
    }
}

// ---------------- V transpose with k-order permutation -----------------------
// VT[d][32-block B][o] = V[s = 32B + sigma(o)][d], sigma: o=Q*8+e -> (e>>2)*16+Q*4+(e&3).
__global__ __launch_bounds__(256) void transpose_v(const __bf16* __restrict__ QKV,
                                                   __bf16* __restrict__ VT) {
    __shared__ __bf16 tile[64][72];
    const int r0 = blockIdx.x * 64;
    const int s0 = blockIdx.y * 64;
    const int t  = threadIdx.x;
    #pragma unroll
    for (int cc = 0; cc < 2; cc++) {
        int c = t + cc * 256;
        int i = c >> 3;
        int j8 = (c & 7) * 8;
        bf16x8 v = *(const bf16x8*)(QKV + (size_t)(s0 + i) * QKVN + (HIDDEN + KVDIM) + r0 + j8);
        *(bf16x8*)&tile[i][j8] = v;
    }
    __syncthreads();
    #pragma unroll
    for (int cc = 0; cc < 2; cc++) {
        int c = t + cc * 256;
        int d = c >> 3;
        int m = c & 7;                 // output 8-elem chunk within 64 s-positions
        bf16x8 vv;
        #pragma unroll
        for (int tt = 0; tt < 8; tt++) {
            int sl = (m >> 2) * 32 + (tt >> 2) * 16 + (m & 3) * 4 + (tt & 3);
            vv[tt] = tile[sl][d];
        }
        *(bf16x8*)(VT + (size_t)(r0 + d) * MROWS + s0 + m * 8) = vv;
    }
}

// ---------------- flash attention: 128-row blocks, 2 col-blocks/wave ----------
// R7 post-mortem: LDS pipe was the wall (8 b128/wave-iter for only 16 q-rows;
// all 4 waves read identical K/V fragments). Now one block = 128 q-rows, each
// wave owns 32 rows as TWO 16-col MFMA blocks (A=[qb,qb+16), B=[qb+16,qb+32))
// sharing one set of K/V fragment reads: LDS bytes + barriers + staging per
// q-row HALVED (iterations 67.6K -> 34.8K). Per iter/wave: 8 b128, 18 MFMA,
// 16 exp2. Grid 1024 = exactly 4 blocks/CU (LDS 24 KB allows 6); per-CU work
// balanced via arithmetic tile map (groups {g,g+4,g+8,g+12} sum(t+1)=34 each).
// Fully-masked sub-blocks skipped via wave-uniform doA/doB gates.
// V reads now XOR-swizzled like K (same involution: source srcc8, read swz).
// QK^T swapped (mfma(K,Q)); P = exp2(S) packed in-register to ONE bf16x8 and
// fed to K=32 MFMAs for PV (V sigma-permuted) and the ones-rowsum.
// Ks/Vs triple-buffered; raw s_barrier + counted s_waitcnt vmcnt(2).
// Q pre-scaled by (1/8)*log2(e); fixed-max exp2 softmax.
__global__ __launch_bounds__(256) void flash_attn(const __bf16* __restrict__ QKV,
                                                  const __bf16* __restrict__ VT,
                                                  __bf16* __restrict__ O) {
    const int bid  = blockIdx.x;
    const int g    = bid >> 6;                // 16 groups of 64 (all b,h per group)
    // balanced map: {15,14,13,12, 8,9,10,11, 7,6,5,4, 0,1,2,3}
    const int t    = ((g >> 2) & 1) ? ((g & 8) ? (g - 12) : (g + 4)) : (15 - g);
    const int head = (bid >> 1) & 31;
    const int b    = bid & 1;
    const int kvh  = head >> 2;
    const int tid  = threadIdx.x;
    const int lane = tid & 63;
    const int w    = tid >> 6;
    const int col  = lane & 15;
    const int quad = lane >> 4;

    const int qb   = t * 128 + w * 32;        // wave's rows: A=[qb,qb+16), B=[qb+16,qb+32)
    const int n32  = (t + 1) * 4;             // k-tiles (32-granular), >=4

    __shared__ __bf16 Ks[3][2][32][32];  // [buf][d-half][kpos][d32]  12 KB
    __shared__ __bf16 Vs[3][64][32];     // [buf][d][k-perm o]        12 KB

    const size_t qOA = (size_t)(b * SEQ + qb + col) * QKVN + head * HD;
    const size_t qOB = qOA + (size_t)16 * QKVN;
    bf16x8 aqA0 = *(const bf16x8*)(QKV + qOA + quad * 8);
    bf16x8 aqA1 = *(const bf16x8*)(QKV + qOA + 32 + quad * 8);
    bf16x8 aqB0 = *(const bf16x8*)(QKV + qOB + quad * 8);
    bf16x8 aqB1 = *(const bf16x8*)(QKV + qOB + 32 + quad * 8);

    bf16x8 ones8;
    #pragma unroll
    for (int j = 0; j < 8; j++) ones8[j] = (__bf16)1.0f;

    f32x4 oA[4], oB[4];
    #pragma unroll
    for (int dn = 0; dn < 4; dn++) { oA[dn] = (f32x4){0.f,0.f,0.f,0.f}; oB[dn] = (f32x4){0.f,0.f,0.f,0.f}; }
    f32x4 lsumA = (f32x4){0.f,0.f,0.f,0.f};
    f32x4 lsumB = (f32x4){0.f,0.f,0.f,0.f};

    const int lrow = lane >> 2;                        // 0..15 (staging row)
    const int srcc8 = (((lane & 3) ^ (lrow & 3)) * 8); // swizzled source chunk (K and V)
    const int swz   = (quad ^ (col & 3)) * 8;          // swizzled K/V read chunk
    const size_t bS = (size_t)b * SEQ;

    // Waves 0,1 stage K d-halves 0,1; waves 2,3 stage V d 0-31 / 32-63.
    const __bf16 *g0, *g1;
    size_t gstep;
    if (w < 2) {
        g0 = QKV + (bS + lrow) * QKVN + HIDDEN + kvh * HD + w * 32 + srcc8;
        g1 = g0 + (size_t)16 * QKVN;
        gstep = (size_t)32 * QKVN;
    } else {
        g0 = VT + (size_t)(kvh * HD + (w - 2) * 32 + lrow) * MROWS + bS + srcc8;
        g1 = g0 + (size_t)16 * MROWS;
        gstep = 32;
    }

    auto stage = [&](int sb) {
        if (w < 2) {
            gld16(g0, &Ks[sb][w][0][0]);
            gld16(g1, &Ks[sb][w][16][0]);
        } else {
            gld16(g0, &Vs[sb][(w - 2) * 32][0]);
            gld16(g1, &Vs[sb][(w - 2) * 32 + 16][0]);
        }
        g0 += gstep; g1 += gstep;
    };

    stage(0);
    stage(1);
    int cur = 0, nx2 = 2;
    for (int kt = 0; kt < n32; kt++) {
        const int kbase = kt * 32;
        // own stage(kt) landed (kt+1 still in flight); tail iterations drain
        if (kt + 1 < n32) { __asm__ volatile("s_waitcnt vmcnt(2)" ::: "memory"); }
        else              { __asm__ volatile("s_waitcnt vmcnt(0)" ::: "memory"); }
        __builtin_amdgcn_s_barrier();         // all waves' stage(kt) visible
        __asm__ volatile("" ::: "memory");
        if (kt + 2 < n32) stage(nx2);         // overwrites (kt-1)%3: safe post-barrier

        const bool doB = (kbase <= qb + 31);  // wave-uniform: any unmasked B entry
        const bool doA = (kbase <= qb + 15);  // wave-uniform: any unmasked A entry

        if (doB) {
            // S^T via swapped operands: lane holds S[q][k=kbase+j*16+quad*4+r]
            f32x4 sA[2], sB[2];
            #pragma unroll
            for (int j = 0; j < 2; j++) { sA[j] = (f32x4){0.f,0.f,0.f,0.f}; sB[j] = (f32x4){0.f,0.f,0.f,0.f}; }
            __builtin_amdgcn_s_setprio(1);
            #pragma unroll
            for (int j = 0; j < 2; j++) {
                bf16x8 bk0 = *(const bf16x8*)&Ks[cur][0][j*16 + col][swz];
                bf16x8 bk1 = *(const bf16x8*)&Ks[cur][1][j*16 + col][swz];
                sB[j] = mfma32(bk0, aqB0, sB[j]);
                sB[j] = mfma32(bk1, aqB1, sB[j]);
                if (doA) {
                    sA[j] = mfma32(bk0, aqA0, sA[j]);
                    sA[j] = mfma32(bk1, aqA1, sA[j]);
                }
            }
            __builtin_amdgcn_s_setprio(0);

            // diagonal masking: k = kbase + j*16 + quad*4 + r vs q
            if (kbase + 31 > qb + 16) {
                #pragma unroll
                for (int j = 0; j < 2; j++)
                    #pragma unroll
                    for (int r = 0; r < 4; r++)
                        if (kbase + j*16 + quad*4 + r > qb + 16 + col) sB[j][r] = -1e30f;
            }
            if (doA && (kbase + 31 > qb)) {
                #pragma unroll
                for (int j = 0; j < 2; j++)
                    #pragma unroll
                    for (int r = 0; r < 4; r++)
                        if (kbase + j*16 + quad*4 + r > qb + col) sA[j][r] = -1e30f;
            }

            // P in-register as one K=32 A-fragment each: elem e=j*4+r at hw k=quad*8+e
            bf16x8 paB, paA;
            #pragma unroll
            for (int j = 0; j < 2; j++)
                #pragma unroll
                for (int r = 0; r < 4; r++)
                    paB[j*4 + r] = (__bf16)__builtin_amdgcn_exp2f(sB[j][r]);
            if (doA) {
                #pragma unroll
                for (int j = 0; j < 2; j++)
                    #pragma unroll
                    for (int r = 0; r < 4; r++)
                        paA[j*4 + r] = (__bf16)__builtin_amdgcn_exp2f(sA[j][r]);
            }

            __builtin_amdgcn_s_setprio(1);
            lsumB = mfma32(paB, ones8, lsumB);
            if (doA) lsumA = mfma32(paA, ones8, lsumA);
            #pragma unroll
            for (int dn = 0; dn < 4; dn++) {
                bf16x8 bv = *(const bf16x8*)&Vs[cur][dn*16 + col][swz];
                oB[dn] = mfma32(paB, bv, oB[dn]);
                if (doA) oA[dn] = mfma32(paA, bv, oA[dn]);
            }
            __builtin_amdgcn_s_setprio(0);
        }

        cur = (cur == 2) ? 0 : cur + 1;
        nx2 = (nx2 == 2) ? 0 : nx2 + 1;
    }

    #pragma unroll
    for (int r = 0; r < 4; r++) {
        float invA = 1.0f / lsumA[r];
        float invB = 1.0f / lsumB[r];
        __bf16* opA = O + (size_t)(b * SEQ + qb + quad*4 + r) * HIDDEN + head * HD;
        __bf16* opB = O + (size_t)(b * SEQ + qb + 16 + quad*4 + r) * HIDDEN + head * HD;
        #pragma unroll
        for (int dn = 0; dn < 4; dn++) {
            opA[dn*16 + col] = (__bf16)(oA[dn][r] * invA);
            opB[dn*16 + col] = (__bf16)(oB[dn][r] * invB);
        }
    }
}

// ---------------- launch ----------------
extern "C" void kernel_launch(void* const* d_in, const int* in_sizes, int n_in,
                              void* d_out, int out_size, void* d_ws, size_t ws_size,
                              hipStream_t stream) {
    const float* x  = (const float*)d_in[0];
    const float* Wq = (const float*)d_in[1];
    const float* Wk = (const float*)d_in[2];
    const float* Wv = (const float*)d_in[3];
    const float* Wo = (const float*)d_in[4];
    float* out = (float*)d_out;

    __bf16* p    = (__bf16*)d_ws;
    __bf16* xb   = p; p += (size_t)MROWS * HIDDEN;
    __bf16* wqkv = p; p += (size_t)QKVN * HIDDEN;
    __bf16* wob  = p; p += (size_t)HIDDEN * HIDDEN;
    __bf16* qkv  = p; p += (size_t)MROWS * QKVN;
    __bf16* vt   = p; p += (size_t)KVDIM * MROWS;
    __bf16* aob  = xb;   // alias: x not needed post-projection

    const float qscale = 0.125f * 1.4426950408889634f;
    cast_all<<<18432, 256, 0, stream>>>(x, Wq, Wk, Wv, Wo, xb, wqkv, wob, qscale);

    gemm256<<<dim3(QKVN/192, MROWS/256), 512, 0, stream>>>(xb, wqkv, qkv, MROWS, QKVN, HIDDEN);
    transpose_v<<<dim3(KVDIM/64, MROWS/64), dim3(256), 0, stream>>>(qkv, vt);
    flash_attn<<<BATCH * NHEADS * (SEQ/128), dim3(256), 0, stream>>>(qkv, vt, aob);
    gemm128<float><<<dim3(HIDDEN/128, MROWS/128), dim3(256), 0, stream>>>(aob, wob, out, MROWS, HIDDEN, HIDDEN);
}